// Round 4
// baseline (105.890 us; speedup 1.0000x reference)
//
#include <hip/hip_runtime.h>

typedef float f32x4 __attribute__((ext_vector_type(4)));

#define T_LEN   262144
#define NTAG    128
#define LCH     8                  // chunk length
#define BURN    12                 // burn-in steps
#define NSTEP   (LCH + BURN)       // 20
#define NCHUNK  (T_LEN / LCH)      // 32768
#define NWAVE   (NCHUNK / 16)      // 2048 (16 chunks per wave)
#define NFWDB   (NWAVE / 4)        // 512 forward blocks (first in grid)
#define NSCOREB 256                // score blocks
#define NBLK    (NFWDB + NSCOREB)  // 768

// ---------------------------------------------------------------------------
// Wave-autonomous forward algorithm, fp8 matrix pipe.
// One wave owns 16 chunks. Per step: v = Q^T p via 8rt x 4kt
// mfma_f32_16x16x32_fp8_fp8 (A = Q^T fp8 in 64 VGPRs, loaded once),
// u = v * exp(emit_t), m = max(u) (lane-local + shfl 16/32),
// p' = u/m packed to fp8 B-frags, acc += log(m) on the chunk's own range.
// A-pack and B-pack use the SAME assumed k-order, so the contraction is
// correct under any hardware k-permutation. No LDS, no barriers in loop.
// ---------------------------------------------------------------------------
__global__ __launch_bounds__(256, 2) void crf_all(
    const float* __restrict__ emit, const int* __restrict__ y,
    const float* __restrict__ trans, const float* __restrict__ strans,
    const float* __restrict__ etrans, double* __restrict__ ws,
    float* __restrict__ out)
{
  if (blockIdx.x < NFWDB) {
    // ---------------- forward path ----------------
    const int w   = threadIdx.x >> 6;
    const int l   = threadIdx.x & 63;
    const int col = l & 15;                  // chunk column
    const int grp = l >> 4;                  // lane group
    const int gw  = blockIdx.x * 4 + w;      // global wave id
    const int gc  = gw * 16 + col;           // this lane's global chunk

    // --- A = Q^T fp8 fragments (one-time). byte j of tile (rt,kt) holds
    //     k = 32kt + 4grp + (j&3) + 16*(j>>2), row m = 16rt + col. ---
    long a[8][4];
#pragma unroll
    for (int rt = 0; rt < 8; ++rt) {
      const int outtag = 16 * rt + col;
#pragma unroll
      for (int kt = 0; kt < 4; ++kt) {
        float q[8];
#pragma unroll
        for (int j = 0; j < 8; ++j) {
          const int k = 32 * kt + 4 * grp + (j & 3) + 16 * (j >> 2);
          q[j] = __expf(trans[k * NTAG + outtag]);
        }
        unsigned lo = (unsigned)__builtin_amdgcn_cvt_pk_fp8_f32(q[0], q[1], 0, false);
        lo = (unsigned)__builtin_amdgcn_cvt_pk_fp8_f32(q[2], q[3], (int)lo, true);
        unsigned hi = (unsigned)__builtin_amdgcn_cvt_pk_fp8_f32(q[4], q[5], 0, false);
        hi = (unsigned)__builtin_amdgcn_cvt_pk_fp8_f32(q[6], q[7], (int)hi, true);
        a[rt][kt] = (long)(((unsigned long long)hi << 32) | lo);
      }
    }

    // --- init: chunk 0 exact (alpha0 = strans + emit[0]); others p = 1 ---
    float u[8][4];
    float acc = 0.f;
    if (gc == 0) {
      float vm = -1e30f;
#pragma unroll
      for (int rt = 0; rt < 8; ++rt)
#pragma unroll
        for (int r = 0; r < 4; ++r) {
          const int tag = 16 * rt + 4 * grp + r;
          u[rt][r] = strans[tag] + emit[tag];
          vm = fmaxf(vm, u[rt][r]);
        }
      vm = fmaxf(vm, __shfl_xor(vm, 16, 64));
      vm = fmaxf(vm, __shfl_xor(vm, 32, 64));
      acc = vm;                              // dc_0
#pragma unroll
      for (int rt = 0; rt < 8; ++rt)
#pragma unroll
        for (int r = 0; r < 4; ++r) u[rt][r] = __expf(u[rt][r] - vm);
    } else {
#pragma unroll
      for (int rt = 0; rt < 8; ++rt)
#pragma unroll
        for (int r = 0; r < 4; ++r) u[rt][r] = 1.0f;
    }
    long b[4];
#pragma unroll
    for (int kt = 0; kt < 4; ++kt) {   // B-pack: same k-order as A-pack
      unsigned lo = (unsigned)__builtin_amdgcn_cvt_pk_fp8_f32(u[2*kt][0], u[2*kt][1], 0, false);
      lo = (unsigned)__builtin_amdgcn_cvt_pk_fp8_f32(u[2*kt][2], u[2*kt][3], (int)lo, true);
      unsigned hi = (unsigned)__builtin_amdgcn_cvt_pk_fp8_f32(u[2*kt+1][0], u[2*kt+1][1], 0, false);
      hi = (unsigned)__builtin_amdgcn_cvt_pk_fp8_f32(u[2*kt+1][2], u[2*kt+1][3], (int)hi, true);
      b[kt] = (long)(((unsigned long long)hi << 32) | lo);
    }

    // --- emit prefetch for step 0 (row index clamped: gc=1 starts <0) ---
    const int t0 = (gc == 0) ? 1 : (gc * LCH - BURN);
    float4 pf[8];
    {
      const float* ep = emit + ((size_t)max(t0, 0) << 7) + 4 * grp;
#pragma unroll
      for (int rt = 0; rt < 8; ++rt) pf[rt] = *(const float4*)(ep + 16 * rt);
    }

    // --- main loop ---
#pragma unroll 1
    for (int s = 0; s < NSTEP; ++s) {
      // phase 1: v = Q^T p (8 independent accumulator chains, 4-deep)
      f32x4 c[8];
#pragma unroll
      for (int rt = 0; rt < 8; ++rt) c[rt] = (f32x4){0.f, 0.f, 0.f, 0.f};
#pragma unroll
      for (int kt = 0; kt < 4; ++kt)
#pragma unroll
        for (int rt = 0; rt < 8; ++rt)
          c[rt] = __builtin_amdgcn_mfma_f32_16x16x32_fp8_fp8(a[rt][kt], b[kt], c[rt], 0, 0, 0);

      // phase 2a: E = exp(emit) (consume pf), then issue next prefetch
      float e[8][4];
#pragma unroll
      for (int rt = 0; rt < 8; ++rt) {
        e[rt][0] = __expf(pf[rt].x);
        e[rt][1] = __expf(pf[rt].y);
        e[rt][2] = __expf(pf[rt].z);
        e[rt][3] = __expf(pf[rt].w);
      }
      if (s < NSTEP - 1) {
        const int tn = t0 + s + 1;
        const float* ep = emit + ((size_t)max(tn, 0) << 7) + 4 * grp;
#pragma unroll
        for (int rt = 0; rt < 8; ++rt) pf[rt] = *(const float4*)(ep + 16 * rt);
      }

      // phase 2b: u = v*E, m = max(u), acc += log(m), p' = u/m -> fp8 B
      float vm = -1e30f;
#pragma unroll
      for (int rt = 0; rt < 8; ++rt)
#pragma unroll
        for (int r = 0; r < 4; ++r) {
          u[rt][r] = c[rt][r] * e[rt][r];
          vm = fmaxf(vm, u[rt][r]);
        }
      vm = fmaxf(vm, __shfl_xor(vm, 16, 64));
      vm = fmaxf(vm, __shfl_xor(vm, 32, 64));
      const bool on = (gc == 0) ? (s <= LCH - 2) : (s >= BURN);
      if (on) acc += __logf(vm);
      const float rinv = __frcp_rn(vm);
#pragma unroll
      for (int kt = 0; kt < 4; ++kt) {
        float s0 = u[2*kt][0] * rinv,   s1 = u[2*kt][1] * rinv;
        float s2 = u[2*kt][2] * rinv,   s3 = u[2*kt][3] * rinv;
        float s4 = u[2*kt+1][0] * rinv, s5 = u[2*kt+1][1] * rinv;
        float s6 = u[2*kt+1][2] * rinv, s7 = u[2*kt+1][3] * rinv;
        unsigned lo = (unsigned)__builtin_amdgcn_cvt_pk_fp8_f32(s0, s1, 0, false);
        lo = (unsigned)__builtin_amdgcn_cvt_pk_fp8_f32(s2, s3, (int)lo, true);
        unsigned hi = (unsigned)__builtin_amdgcn_cvt_pk_fp8_f32(s4, s5, 0, false);
        hi = (unsigned)__builtin_amdgcn_cvt_pk_fp8_f32(s6, s7, (int)hi, true);
        b[kt] = (long)(((unsigned long long)hi << 32) | lo);
      }

      // final-state LSE (last chunk, after last normalize)
      if (s == NSTEP - 1 && gc == NCHUNK - 1) {
        float lv = 0.f;
#pragma unroll
        for (int rt = 0; rt < 8; ++rt)
#pragma unroll
          for (int r = 0; r < 4; ++r)
            lv += (u[rt][r] * rinv) * __expf(etrans[16 * rt + 4 * grp + r]);
        lv += __shfl_xor(lv, 16, 64);
        lv += __shfl_xor(lv, 32, 64);
        if (l == 15) atomicAdd(&ws[2], (double)lv);
      }
    }

    // --- per-wave dc reduction (acc identical across the 4 grp lanes) ---
    float av = (grp == 0) ? acc : 0.f;
#pragma unroll
    for (int off = 1; off < 64; off <<= 1) av += __shfl_xor(av, off, 64);
    if (l == 0) atomicAdd(&ws[0], (double)av);
  } else {
    // ---------------- score path ----------------
    __shared__ float sred[4];
    int idx0 = (blockIdx.x - NFWDB) * 256 + threadIdx.x;   // 0..65535
    float v = 0.f;
    for (int t = idx0; t < T_LEN - 1; t += NSCOREB * 256) {
      int yt = y[t], yn = y[t + 1];
      v += trans[yt * NTAG + yn] + emit[(size_t)t * NTAG + yt];
    }
    if (idx0 == 0) {
      int yl = y[T_LEN - 1];
      v += strans[y[0]] + etrans[yl] + emit[(size_t)(T_LEN - 1) * NTAG + yl];
    }
#pragma unroll
    for (int off = 1; off < 64; off <<= 1) v += __shfl_xor(v, off, 64);
    if ((threadIdx.x & 63) == 0) sred[threadIdx.x >> 6] = v;
    __syncthreads();
    if (threadIdx.x == 0)
      atomicAdd(&ws[1], (double)(sred[0] + sred[1] + sred[2] + sred[3]));
  }

  // ---------------- completion: last block writes the output ----------------
  __syncthreads();
  if (threadIdx.x == 0) {
    __threadfence();
    unsigned t = atomicAdd((unsigned*)&ws[3], 1u);
    if (t == NBLK - 1) {
      double d0 = atomicAdd(&ws[0], 0.0);   // sum dc
      double d1 = atomicAdd(&ws[1], 0.0);   // path score
      double d2 = atomicAdd(&ws[2], 0.0);   // final sum p*e^etrans
      out[0] = (float)(d0 + log(d2) - d1);
    }
  }
}

// ---------------------------------------------------------------------------
extern "C" void kernel_launch(void* const* d_in, const int* in_sizes, int n_in,
                              void* d_out, int out_size, void* d_ws, size_t ws_size,
                              hipStream_t stream)
{
  const float* emit   = (const float*)d_in[0];
  const int*   y      = (const int*)d_in[1];
  const float* trans  = (const float*)d_in[2];
  const float* strans = (const float*)d_in[3];
  const float* etrans = (const float*)d_in[4];
  float*  out = (float*)d_out;
  double* ws  = (double*)d_ws;

  hipMemsetAsync(ws, 0, 4 * sizeof(double), stream);
  crf_all<<<dim3(NBLK), dim3(256), 0, stream>>>(
      emit, y, trans, strans, etrans, ws, out);
}

// Round 5
// 92.532 us; speedup vs baseline: 1.1444x; 1.1444x over previous
//
#include <hip/hip_runtime.h>

typedef float f32x4 __attribute__((ext_vector_type(4)));

#define T_LEN   262144
#define NTAG    128
#define LCH     8                  // chunk length
#define BURN    8                  // burn-in steps
#define NSTEP   (LCH + BURN)       // 16
#define NCHUNK  (T_LEN / LCH)      // 32768
#define NWAVE   (NCHUNK / 16)      // 2048 (16 chunks per wave)
#define NFWDB   (NWAVE / 4)        // 512 forward blocks (first in grid)
#define NSCOREB 256                // score blocks
#define NBLK    (NFWDB + NSCOREB)  // 768

// ---------------------------------------------------------------------------
// Wave-autonomous forward algorithm, fp8 matrix pipe, spill-free liveness.
// One wave owns 16 chunks. Per step: c = Q^T p (8rt x 4kt fp8 MFMA, A in 64
// VGPRs loaded once), c *= exp(emit_t) in place, m = max(c) (lane + shfl),
// acc += log(m) on own range, B' = fp8(c/m). A-pack and B-pack share the same
// assumed k-order so the contraction is layout-invariant. No LDS/barriers.
// ---------------------------------------------------------------------------
__global__ __launch_bounds__(256, 1) void crf_all(
    const float* __restrict__ emit, const int* __restrict__ y,
    const float* __restrict__ trans, const float* __restrict__ strans,
    const float* __restrict__ etrans, double* __restrict__ ws,
    float* __restrict__ out)
{
  if (blockIdx.x < NFWDB) {
    // ---------------- forward path ----------------
    const int w   = threadIdx.x >> 6;
    const int l   = threadIdx.x & 63;
    const int col = l & 15;                  // chunk column
    const int grp = l >> 4;                  // lane group
    const int gw  = blockIdx.x * 4 + w;      // global wave id
    const int gc  = gw * 16 + col;           // this lane's global chunk

    // --- A = Q^T fp8 fragments (one-time). byte j of tile (rt,kt) holds
    //     k = 32kt + 4grp + (j&3) + 16*(j>>2), row m = 16rt + col. ---
    long a[8][4];
#pragma unroll
    for (int rt = 0; rt < 8; ++rt) {
      const int outtag = 16 * rt + col;
#pragma unroll
      for (int kt = 0; kt < 4; ++kt) {
        float q[8];
#pragma unroll
        for (int j = 0; j < 8; ++j) {
          const int k = 32 * kt + 4 * grp + (j & 3) + 16 * (j >> 2);
          q[j] = __expf(trans[k * NTAG + outtag]);
        }
        unsigned lo = (unsigned)__builtin_amdgcn_cvt_pk_fp8_f32(q[0], q[1], 0, false);
        lo = (unsigned)__builtin_amdgcn_cvt_pk_fp8_f32(q[2], q[3], (int)lo, true);
        unsigned hi = (unsigned)__builtin_amdgcn_cvt_pk_fp8_f32(q[4], q[5], 0, false);
        hi = (unsigned)__builtin_amdgcn_cvt_pk_fp8_f32(q[6], q[7], (int)hi, true);
        a[rt][kt] = (long)(((unsigned long long)hi << 32) | lo);
      }
    }

    // --- init: chunk 0 exact (alpha0 = strans + emit[0]); others p = 1 ---
    float acc = 0.f;
    long b[4];
    {
      float u[8][4];
      if (gc == 0) {
        float vm = -1e30f;
#pragma unroll
        for (int rt = 0; rt < 8; ++rt)
#pragma unroll
          for (int r = 0; r < 4; ++r) {
            const int tag = 16 * rt + 4 * grp + r;
            u[rt][r] = strans[tag] + emit[tag];
            vm = fmaxf(vm, u[rt][r]);
          }
        vm = fmaxf(vm, __shfl_xor(vm, 16, 64));
        vm = fmaxf(vm, __shfl_xor(vm, 32, 64));
        acc = vm;                            // dc_0
#pragma unroll
        for (int rt = 0; rt < 8; ++rt)
#pragma unroll
          for (int r = 0; r < 4; ++r) u[rt][r] = __expf(u[rt][r] - vm);
      } else {
#pragma unroll
        for (int rt = 0; rt < 8; ++rt)
#pragma unroll
          for (int r = 0; r < 4; ++r) u[rt][r] = 1.0f;
      }
#pragma unroll
      for (int kt = 0; kt < 4; ++kt) {   // B-pack: same k-order as A-pack
        unsigned lo = (unsigned)__builtin_amdgcn_cvt_pk_fp8_f32(u[2*kt][0], u[2*kt][1], 0, false);
        lo = (unsigned)__builtin_amdgcn_cvt_pk_fp8_f32(u[2*kt][2], u[2*kt][3], (int)lo, true);
        unsigned hi = (unsigned)__builtin_amdgcn_cvt_pk_fp8_f32(u[2*kt+1][0], u[2*kt+1][1], 0, false);
        hi = (unsigned)__builtin_amdgcn_cvt_pk_fp8_f32(u[2*kt+1][2], u[2*kt+1][3], (int)hi, true);
        b[kt] = (long)(((unsigned long long)hi << 32) | lo);
      }
    }

    // --- emit prefetch for step 0.  Step s consumes emit row t0+s. ---
    const int t0 = (gc == 0) ? 1 : (gc * LCH - BURN);
    float4 pf[8];
    {
      const float* ep = emit + ((size_t)t0 << 7) + 4 * grp;
#pragma unroll
      for (int rt = 0; rt < 8; ++rt) pf[rt] = *(const float4*)(ep + 16 * rt);
    }

    // --- main loop ---
#pragma unroll 1
    for (int s = 0; s < NSTEP; ++s) {
      // phase 1: c = Q^T p (8 independent 4-deep accumulator chains)
      f32x4 c[8];
#pragma unroll
      for (int rt = 0; rt < 8; ++rt) c[rt] = (f32x4){0.f, 0.f, 0.f, 0.f};
#pragma unroll
      for (int kt = 0; kt < 4; ++kt)
#pragma unroll
        for (int rt = 0; rt < 8; ++rt)
          c[rt] = __builtin_amdgcn_mfma_f32_16x16x32_fp8_fp8(a[rt][kt], b[kt], c[rt], 0, 0, 0);

      // phase 2a: c *= exp(emit) in place (consume pf), track max
      float vm = -1e30f;
#pragma unroll
      for (int rt = 0; rt < 8; ++rt) {
        c[rt][0] *= __expf(pf[rt].x);
        c[rt][1] *= __expf(pf[rt].y);
        c[rt][2] *= __expf(pf[rt].z);
        c[rt][3] *= __expf(pf[rt].w);
        vm = fmaxf(vm, fmaxf(fmaxf(c[rt][0], c[rt][1]), fmaxf(c[rt][2], c[rt][3])));
      }
      // issue next prefetch immediately after pf is consumed
      if (s < NSTEP - 1) {
        const float* ep = emit + ((size_t)(t0 + s + 1) << 7) + 4 * grp;
#pragma unroll
        for (int rt = 0; rt < 8; ++rt) pf[rt] = *(const float4*)(ep + 16 * rt);
      }

      // phase 2b: cross-lane max, dc accumulate, repack B' = fp8(c/m)
      vm = fmaxf(vm, __shfl_xor(vm, 16, 64));
      vm = fmaxf(vm, __shfl_xor(vm, 32, 64));
      const bool on = (gc == 0) ? (s <= LCH - 2) : (s >= BURN);
      if (on) acc += __logf(vm);
      const float rinv = __frcp_rn(vm);
#pragma unroll
      for (int kt = 0; kt < 4; ++kt) {
        const float s0 = c[2*kt][0] * rinv,   s1 = c[2*kt][1] * rinv;
        const float s2 = c[2*kt][2] * rinv,   s3 = c[2*kt][3] * rinv;
        const float s4 = c[2*kt+1][0] * rinv, s5 = c[2*kt+1][1] * rinv;
        const float s6 = c[2*kt+1][2] * rinv, s7 = c[2*kt+1][3] * rinv;
        unsigned lo = (unsigned)__builtin_amdgcn_cvt_pk_fp8_f32(s0, s1, 0, false);
        lo = (unsigned)__builtin_amdgcn_cvt_pk_fp8_f32(s2, s3, (int)lo, true);
        unsigned hi = (unsigned)__builtin_amdgcn_cvt_pk_fp8_f32(s4, s5, 0, false);
        hi = (unsigned)__builtin_amdgcn_cvt_pk_fp8_f32(s6, s7, (int)hi, true);
        b[kt] = (long)(((unsigned long long)hi << 32) | lo);
      }

      // final-state LSE (last chunk, after last normalize)
      if (s == NSTEP - 1 && gc == NCHUNK - 1) {
        float lv = 0.f;
#pragma unroll
        for (int rt = 0; rt < 8; ++rt)
#pragma unroll
          for (int r = 0; r < 4; ++r)
            lv += (c[rt][r] * rinv) * __expf(etrans[16 * rt + 4 * grp + r]);
        lv += __shfl_xor(lv, 16, 64);
        lv += __shfl_xor(lv, 32, 64);
        if (l == 15) atomicAdd(&ws[2], (double)lv);
      }
    }

    // --- per-wave dc reduction (acc identical across the 4 grp lanes) ---
    float av = (grp == 0) ? acc : 0.f;
#pragma unroll
    for (int off = 1; off < 64; off <<= 1) av += __shfl_xor(av, off, 64);
    if (l == 0) atomicAdd(&ws[0], (double)av);
  } else {
    // ---------------- score path ----------------
    __shared__ float sred[4];
    int idx0 = (blockIdx.x - NFWDB) * 256 + threadIdx.x;   // 0..65535
    float v = 0.f;
    for (int t = idx0; t < T_LEN - 1; t += NSCOREB * 256) {
      int yt = y[t], yn = y[t + 1];
      v += trans[yt * NTAG + yn] + emit[(size_t)t * NTAG + yt];
    }
    if (idx0 == 0) {
      int yl = y[T_LEN - 1];
      v += strans[y[0]] + etrans[yl] + emit[(size_t)(T_LEN - 1) * NTAG + yl];
    }
#pragma unroll
    for (int off = 1; off < 64; off <<= 1) v += __shfl_xor(v, off, 64);
    if ((threadIdx.x & 63) == 0) sred[threadIdx.x >> 6] = v;
    __syncthreads();
    if (threadIdx.x == 0)
      atomicAdd(&ws[1], (double)(sred[0] + sred[1] + sred[2] + sred[3]));
  }

  // ---------------- completion: last block writes the output ----------------
  __syncthreads();
  if (threadIdx.x == 0) {
    __threadfence();
    unsigned t = atomicAdd((unsigned*)&ws[3], 1u);
    if (t == NBLK - 1) {
      double d0 = atomicAdd(&ws[0], 0.0);   // sum dc
      double d1 = atomicAdd(&ws[1], 0.0);   // path score
      double d2 = atomicAdd(&ws[2], 0.0);   // final sum p*e^etrans
      out[0] = (float)(d0 + log(d2) - d1);
    }
  }
}

// ---------------------------------------------------------------------------
extern "C" void kernel_launch(void* const* d_in, const int* in_sizes, int n_in,
                              void* d_out, int out_size, void* d_ws, size_t ws_size,
                              hipStream_t stream)
{
  const float* emit   = (const float*)d_in[0];
  const int*   y      = (const int*)d_in[1];
  const float* trans  = (const float*)d_in[2];
  const float* strans = (const float*)d_in[3];
  const float* etrans = (const float*)d_in[4];
  float*  out = (float*)d_out;
  double* ws  = (double*)d_ws;

  hipMemsetAsync(ws, 0, 4 * sizeof(double), stream);
  crf_all<<<dim3(NBLK), dim3(256), 0, stream>>>(
      emit, y, trans, strans, etrans, ws, out);
}

// Round 6
// 82.385 us; speedup vs baseline: 1.2853x; 1.1232x over previous
//
#include <hip/hip_runtime.h>

typedef float f32x4 __attribute__((ext_vector_type(4)));

#define T_LEN   262144
#define NTAG    128
#define LCH     8                  // chunk length
#define BURN    8                  // burn-in steps
#define NSTEP   16                 // LCH + BURN
#define NCHUNK  (T_LEN / LCH)      // 32768
#define NWAVE   (NCHUNK / 16)      // 2048 (16 chunks per wave)
#define NFWDB   (NWAVE / 4)        // 512 forward blocks
#define NSCOREB 256
#define C9      6.23832462503951f  // 9 ln2 (per-step 2^-9 normalizer)
#define K63LN2  43.66827237527655f // 63 ln2
#define K72LN2  49.90659700060892f // 72 ln2

// ---------------------------------------------------------------------------
// Setup: Q = exp(trans) packed to fp8 A-fragments, coalesced layout
// q4[j][lane], j = rt*2 + kt/2 (each uint4 = tiles a[rt][2k],a[rt][2k+1]).
// Byte j of tile (rt,kt) holds k = 32kt+4grp+(j&3)+16*(j>>2), row = 16rt+col.
// ---------------------------------------------------------------------------
__global__ void crf_setup(const float* __restrict__ trans, uint4* __restrict__ q4)
{
  const int l = threadIdx.x;           // 64 threads
  const int col = l & 15, grp = l >> 4;
  for (int rt = 0; rt < 8; ++rt) {
    const int outtag = 16 * rt + col;
    for (int kp = 0; kp < 2; ++kp) {
      unsigned r[4];
      for (int h = 0; h < 2; ++h) {
        const int kt = kp * 2 + h;
        float q[8];
        for (int j = 0; j < 8; ++j) {
          const int k = 32 * kt + 4 * grp + (j & 3) + 16 * (j >> 2);
          q[j] = __expf(trans[k * NTAG + outtag]);
        }
        unsigned lo = (unsigned)__builtin_amdgcn_cvt_pk_fp8_f32(q[0], q[1], 0, false);
        lo = (unsigned)__builtin_amdgcn_cvt_pk_fp8_f32(q[2], q[3], (int)lo, true);
        unsigned hi = (unsigned)__builtin_amdgcn_cvt_pk_fp8_f32(q[4], q[5], 0, false);
        hi = (unsigned)__builtin_amdgcn_cvt_pk_fp8_f32(q[6], q[7], (int)hi, true);
        r[h * 2] = lo; r[h * 2 + 1] = hi;
      }
      q4[(rt * 2 + kp) * 64 + l] = make_uint4(r[0], r[1], r[2], r[3]);
    }
  }
}

// ---------------------------------------------------------------------------
// Forward: one wave owns 16 chunks, no LDS/barriers. Per step (full unroll):
//   e = exp(emit - 9ln2)  [off recurrence path]
//   prefetch emit row s+2 into ping-pong pf
//   c = Q^T p  (8rt x 4kt fp8 MFMA)
//   w = c*e ; every 4th step: exact rescale w /= max128(w), else scale-free
//   b = fp8(w)
// Telescoped accounting (exact): chunk acc = log vm11 + log vm15 + 72ln2;
// chunk0: m0 + log vm3 + log maxW6 + 63ln2.
// ---------------------------------------------------------------------------
__global__ __launch_bounds__(256, 2) void crf_fwd(
    const float* __restrict__ emit, const float* __restrict__ strans,
    const float* __restrict__ etrans, const uint4* __restrict__ q4,
    double* __restrict__ ws)
{
  const int w_id = threadIdx.x >> 6;
  const int l    = threadIdx.x & 63;
  const int col  = l & 15;
  const int grp  = l >> 4;
  const int gw   = blockIdx.x * 4 + w_id;   // global wave id
  const int gc   = gw * 16 + col;           // this lane's global chunk

  // --- A fragments: 16 coalesced dwordx4 loads ---
  long a[8][4];
#pragma unroll
  for (int rt = 0; rt < 8; ++rt)
#pragma unroll
    for (int kp = 0; kp < 2; ++kp) {
      uint4 v = q4[(rt * 2 + kp) * 64 + l];
      a[rt][2 * kp]     = (long)(((unsigned long long)v.y << 32) | v.x);
      a[rt][2 * kp + 1] = (long)(((unsigned long long)v.w << 32) | v.z);
    }

  // --- init state: chunk 0 exact; others p = 1 ---
  float m0 = 0.f;
  long b[4];
  {
    float u[8][4];
    if (gw == 0) {                      // wave-uniform; only col==0 lanes special
      float vm = -1e30f;
#pragma unroll
      for (int rt = 0; rt < 8; ++rt)
#pragma unroll
        for (int r = 0; r < 4; ++r) {
          const int tag = 16 * rt + 4 * grp + r;
          u[rt][r] = (col == 0) ? (strans[tag] + emit[tag]) : 0.f;
          vm = fmaxf(vm, u[rt][r]);
        }
      vm = fmaxf(vm, __shfl_xor(vm, 16, 64));
      vm = fmaxf(vm, __shfl_xor(vm, 32, 64));
      m0 = vm;                           // valid for col==0 lanes
#pragma unroll
      for (int rt = 0; rt < 8; ++rt)
#pragma unroll
        for (int r = 0; r < 4; ++r)
          u[rt][r] = (col == 0) ? __expf(u[rt][r] - vm) : 1.0f;
    } else {
#pragma unroll
      for (int rt = 0; rt < 8; ++rt)
#pragma unroll
        for (int r = 0; r < 4; ++r) u[rt][r] = 1.0f;
    }
#pragma unroll
    for (int kt = 0; kt < 4; ++kt) {
      unsigned lo = (unsigned)__builtin_amdgcn_cvt_pk_fp8_f32(u[2*kt][0], u[2*kt][1], 0, false);
      lo = (unsigned)__builtin_amdgcn_cvt_pk_fp8_f32(u[2*kt][2], u[2*kt][3], (int)lo, true);
      unsigned hi = (unsigned)__builtin_amdgcn_cvt_pk_fp8_f32(u[2*kt+1][0], u[2*kt+1][1], 0, false);
      hi = (unsigned)__builtin_amdgcn_cvt_pk_fp8_f32(u[2*kt+1][2], u[2*kt+1][3], (int)hi, true);
      b[kt] = (long)(((unsigned long long)hi << 32) | lo);
    }
  }

  // --- prefetch rows for steps 0 and 1 (per-lane t0) ---
  const int t0 = (gc == 0) ? 1 : (gc * LCH - BURN);
  float4 pf[2][8];
  {
    const float* e0 = emit + ((size_t)t0 << 7) + 4 * grp;
    const float* e1 = emit + ((size_t)(t0 + 1) << 7) + 4 * grp;
#pragma unroll
    for (int rt = 0; rt < 8; ++rt) {
      pf[0][rt] = *(const float4*)(e0 + 16 * rt);
      pf[1][rt] = *(const float4*)(e1 + 16 * rt);
    }
  }

  float acc = 0.f;

  // --- main loop: fully unrolled, all step-branches compile-time ---
#pragma unroll
  for (int s = 0; s < NSTEP; ++s) {
    // e = exp(emit - 9ln2): independent of recurrence, fills MFMA shadow
    float e[8][4];
#pragma unroll
    for (int rt = 0; rt < 8; ++rt) {
      e[rt][0] = __expf(pf[s & 1][rt].x - C9);
      e[rt][1] = __expf(pf[s & 1][rt].y - C9);
      e[rt][2] = __expf(pf[s & 1][rt].z - C9);
      e[rt][3] = __expf(pf[s & 1][rt].w - C9);
    }
    // prefetch row s+2 into the buffer just consumed
    if (s < NSTEP - 2) {
      const float* ep = emit + ((size_t)(t0 + s + 2) << 7) + 4 * grp;
#pragma unroll
      for (int rt = 0; rt < 8; ++rt) pf[s & 1][rt] = *(const float4*)(ep + 16 * rt);
    }

    // c = Q^T p
    f32x4 c[8];
#pragma unroll
    for (int rt = 0; rt < 8; ++rt) c[rt] = (f32x4){0.f, 0.f, 0.f, 0.f};
#pragma unroll
    for (int kt = 0; kt < 4; ++kt)
#pragma unroll
      for (int rt = 0; rt < 8; ++rt)
        c[rt] = __builtin_amdgcn_mfma_f32_16x16x32_fp8_fp8(a[rt][kt], b[kt], c[rt], 0, 0, 0);

    // w = c * e
    float w[8][4];
#pragma unroll
    for (int rt = 0; rt < 8; ++rt)
#pragma unroll
      for (int r = 0; r < 4; ++r) w[rt][r] = c[rt][r] * e[rt][r];

    // rescale every 4th step (exact, accounted); boundary norm at s=6 for chunk0
    if ((s & 3) == 3) {
      float vm = w[0][0];
#pragma unroll
      for (int rt = 0; rt < 8; ++rt)
#pragma unroll
        for (int r = 0; r < 4; ++r) vm = fmaxf(vm, w[rt][r]);
      vm = fmaxf(vm, __shfl_xor(vm, 16, 64));
      vm = fmaxf(vm, __shfl_xor(vm, 32, 64));
      const float lv = __logf(vm);
      if (s == 3)  acc += (gc == 0) ? lv : 0.f;
      if (s == 11) acc += (gc != 0) ? lv : 0.f;
      if (s == 15) acc += (gc != 0) ? lv : 0.f;
      const float rinv = __builtin_amdgcn_rcpf(vm);
#pragma unroll
      for (int rt = 0; rt < 8; ++rt)
#pragma unroll
        for (int r = 0; r < 4; ++r) w[rt][r] *= rinv;

      // final-state LSE: last chunk, after last rescale
      if (s == NSTEP - 1 && gw == NWAVE - 1) {
        float lse = 0.f;
#pragma unroll
        for (int rt = 0; rt < 8; ++rt)
#pragma unroll
          for (int r = 0; r < 4; ++r)
            lse += w[rt][r] * __expf(etrans[16 * rt + 4 * grp + r]);
        lse += __shfl_xor(lse, 16, 64);
        lse += __shfl_xor(lse, 32, 64);
        if (l == 15) atomicAdd(&ws[2], (double)lse);   // col 15 = last chunk
      }
    }
    if (s == 6) {
      if (gw == 0) {                    // chunk0 boundary norm (no rescale)
        float vm = w[0][0];
#pragma unroll
        for (int rt = 0; rt < 8; ++rt)
#pragma unroll
          for (int r = 0; r < 4; ++r) vm = fmaxf(vm, w[rt][r]);
        vm = fmaxf(vm, __shfl_xor(vm, 16, 64));
        vm = fmaxf(vm, __shfl_xor(vm, 32, 64));
        acc += (gc == 0) ? __logf(vm) : 0.f;
      }
    }

    // pack b = fp8(w)
#pragma unroll
    for (int kt = 0; kt < 4; ++kt) {
      unsigned lo = (unsigned)__builtin_amdgcn_cvt_pk_fp8_f32(w[2*kt][0], w[2*kt][1], 0, false);
      lo = (unsigned)__builtin_amdgcn_cvt_pk_fp8_f32(w[2*kt][2], w[2*kt][3], (int)lo, true);
      unsigned hi = (unsigned)__builtin_amdgcn_cvt_pk_fp8_f32(w[2*kt+1][0], w[2*kt+1][1], 0, false);
      hi = (unsigned)__builtin_amdgcn_cvt_pk_fp8_f32(w[2*kt+1][2], w[2*kt+1][3], (int)hi, true);
      b[kt] = (long)(((unsigned long long)hi << 32) | lo);
    }
  }

  // --- per-lane constants + reduce: one copy per chunk (grp==0) ---
  const float accf = acc + ((gc == 0) ? (m0 + K63LN2) : K72LN2);
  float av = (grp == 0) ? accf : 0.f;
#pragma unroll
  for (int off = 1; off < 64; off <<= 1) av += __shfl_xor(av, off, 64);
  if (l == 0) atomicAdd(&ws[0], (double)av);
}

// ---------------------------------------------------------------------------
__global__ void crf_score(const float* __restrict__ emit, const int* __restrict__ y,
                          const float* __restrict__ trans, const float* __restrict__ strans,
                          const float* __restrict__ etrans, double* __restrict__ ws)
{
  __shared__ float sred[4];
  int idx0 = blockIdx.x * 256 + threadIdx.x;
  float v = 0.f;
  for (int t = idx0; t < T_LEN - 1; t += NSCOREB * 256) {
    int yt = y[t], yn = y[t + 1];
    v += trans[yt * NTAG + yn] + emit[(size_t)t * NTAG + yt];
  }
  if (idx0 == 0) {
    int yl = y[T_LEN - 1];
    v += strans[y[0]] + etrans[yl] + emit[(size_t)(T_LEN - 1) * NTAG + yl];
  }
#pragma unroll
  for (int off = 1; off < 64; off <<= 1) v += __shfl_xor(v, off, 64);
  if ((threadIdx.x & 63) == 0) sred[threadIdx.x >> 6] = v;
  __syncthreads();
  if (threadIdx.x == 0)
    atomicAdd(&ws[1], (double)(sred[0] + sred[1] + sred[2] + sred[3]));
}

__global__ void crf_final(const double* __restrict__ ws, float* __restrict__ out)
{
  out[0] = (float)(ws[0] + log(ws[2]) - ws[1]);
}

// ---------------------------------------------------------------------------
extern "C" void kernel_launch(void* const* d_in, const int* in_sizes, int n_in,
                              void* d_out, int out_size, void* d_ws, size_t ws_size,
                              hipStream_t stream)
{
  const float* emit   = (const float*)d_in[0];
  const int*   y      = (const int*)d_in[1];
  const float* trans  = (const float*)d_in[2];
  const float* strans = (const float*)d_in[3];
  const float* etrans = (const float*)d_in[4];
  float*  out = (float*)d_out;
  double* ws  = (double*)d_ws;
  uint4*  q4  = (uint4*)((char*)d_ws + 64);   // 16 KB fp8 A-fragments

  hipMemsetAsync(ws, 0, 4 * sizeof(double), stream);
  crf_setup<<<dim3(1), dim3(64), 0, stream>>>(trans, q4);
  crf_score<<<dim3(NSCOREB), dim3(256), 0, stream>>>(emit, y, trans, strans, etrans, ws);
  crf_fwd<<<dim3(NFWDB), dim3(256), 0, stream>>>(emit, strans, etrans, q4, ws);
  crf_final<<<dim3(1), dim3(1), 0, stream>>>(ws, out);
}